// Round 9
// baseline (582.651 us; speedup 1.0000x reference)
//
#include <hip/hip_runtime.h>
#include <hip/hip_fp16.h>

#define Hn 128
#define Wn 128
#define HWn 16384
#define Cn 64
#define Bn 8
#define NTOT (Bn*Cn*HWn)   /* 8388608 */
#define NPIX (Bn*HWn)      /* 131072  */
#define DTc 0.3f
#define EPSc 1e-5f

__device__ __forceinline__ float sigm(float t){ return 1.0f/(1.0f+__expf(-t)); }
__device__ __forceinline__ float2 uph(unsigned int u){
    __half2 h = *reinterpret_cast<__half2*>(&u); return __half22float2(h);
}
__device__ __forceinline__ unsigned int pkh(float a, float b){
    __half2 h = __floats2half2_rn(a, b); return *reinterpret_cast<unsigned int*>(&h);
}

// ---- pair-interleaved layout: elem (b,c,hw) -> uint index (b*32 + c/2)*HWn + hw, half (c&1)

// ---------------- F/XA/V producer: F=force+0.2*illum, x1=0.09F, v1=0.3F (pair layout) -----
__global__ void fuseF0(const float4* __restrict__ force, const float4* __restrict__ illum,
                       unsigned int* __restrict__ Fu, unsigned int* __restrict__ XAu,
                       unsigned int* __restrict__ Vu)
{
    int t = blockIdx.x * blockDim.x + threadIdx.x;     // [0, NTOT/8)
    int hw4 = t & 4095;                                // hw/4
    int cp  = (t >> 12) & 31;
    int b   = t >> 17;
    int r0 = (b*64 + 2*cp) * 4096 + hw4;               // float4 row indices
    int r1 = r0 + 4096;
    float4 fa = force[r0], fb = force[r1];
    float4 ia = illum[r0], ib = illum[r1];
    float A0 = fa.x + 0.2f*ia.x, A1 = fa.y + 0.2f*ia.y, A2 = fa.z + 0.2f*ia.z, A3 = fa.w + 0.2f*ia.w;
    float B0 = fb.x + 0.2f*ib.x, B1 = fb.y + 0.2f*ib.y, B2 = fb.z + 0.2f*ib.z, B3 = fb.w + 0.2f*ib.w;
    int u4 = ((b*32 + cp) * HWn >> 2) + hw4;           // uint4 index
    uint4 pf, px, pv;
    pf.x = pkh(A0,B0); pf.y = pkh(A1,B1); pf.z = pkh(A2,B2); pf.w = pkh(A3,B3);
    px.x = pkh(0.09f*A0,0.09f*B0); px.y = pkh(0.09f*A1,0.09f*B1);
    px.z = pkh(0.09f*A2,0.09f*B2); px.w = pkh(0.09f*A3,0.09f*B3);
    pv.x = pkh(0.3f*A0,0.3f*B0);   pv.y = pkh(0.3f*A1,0.3f*B1);
    pv.z = pkh(0.3f*A2,0.3f*B2);   pv.w = pkh(0.3f*A3,0.3f*B3);
    reinterpret_cast<uint4*>(Fu)[u4]  = pf;
    reinterpret_cast<uint4*>(XAu)[u4] = px;
    reinterpret_cast<uint4*>(Vu)[u4]  = pv;
}

// ---------------- prep: style constant + weight transposes ----------------
__global__ void prep(const float* __restrict__ style, const float* __restrict__ w1,
                     const float* __restrict__ b1, const float* __restrict__ pw,
                     const float* __restrict__ pw1, const float* __restrict__ pw2,
                     float* __restrict__ w1T, float* __restrict__ c1,
                     float* __restrict__ pwT, float* __restrict__ pw1T,
                     float* __restrict__ pw2T)
{
    int t = threadIdx.x;
    if (t < 32) {
        float s = b1[t];
        for (int k = 0; k < 64; k++) s += w1[t*128 + 64 + k] * style[k];
        c1[t] = s;
    }
    for (int i = t; i < 2048; i += 256) { int c = i >> 5, j = i & 31; w1T[i] = w1[j*128 + c]; }
    for (int i = t; i < 4096; i += 256) {
        int c = i >> 6, k = i & 63;
        pwT[i]  = pw[k*64 + c];
        pw1T[i] = pw1[k*64 + c];
        pw2T[i] = pw2[k*64 + c];
    }
}

// ---------------- hyper encoder: y=0 -> AB (pair layout), y=1 -> GB (linear half2) -------
__global__ void hyper2(const unsigned int* __restrict__ Fu,
                       const float* __restrict__ w1T, const float* __restrict__ c1,
                       const float* __restrict__ w2, const float* __restrict__ b2,
                       const float* __restrict__ w3, const float* __restrict__ b3,
                       uint2* __restrict__ ABu, __half2* __restrict__ GB)
{
    int p = blockIdx.x * blockDim.x + threadIdx.x;
    int b  = p >> 14;
    int sp = p & (HWn - 1);
    int pbase = b * 32 * HWn + sp;                 // uint pair-row base
    int gbase = b * Cn * HWn + sp;                 // linear base (GB)

    float u1[32];
#pragma unroll
    for (int j = 0; j < 32; j++) u1[j] = c1[j];
#pragma unroll 4
    for (int cp = 0; cp < 32; cp++) {
        float2 fc = uph(Fu[pbase + cp*HWn]);
        const float* __restrict__ w0 = w1T + (2*cp)*32;
        const float* __restrict__ w1r = w0 + 32;
#pragma unroll
        for (int j = 0; j < 32; j++) u1[j] += w0[j]*fc.x + w1r[j]*fc.y;
    }
#pragma unroll
    for (int j = 0; j < 32; j++) { float v = u1[j]; u1[j] = v > 0.f ? v : 0.2f*v; }

    float u2[32];
#pragma unroll
    for (int i = 0; i < 32; i++) {
        float s = b2[i];
#pragma unroll
        for (int j = 0; j < 32; j++) s += w2[i*32 + j] * u1[j];
        u2[i] = s > 0.f ? s : 0.2f*s;
    }

    if (blockIdx.y == 0) {
        for (int jp = 0; jp < 32; jp++) {
            int j0 = 2*jp, j1 = 2*jp + 1;
            const float* __restrict__ rw0 = w3 + j0*32;
            const float* __restrict__ rw1 = w3 + j1*32;
            const float* __restrict__ rz0 = w3 + (64 + j0)*32;
            const float* __restrict__ rz1 = w3 + (64 + j1)*32;
            float pw0 = b3[j0], pw1v = b3[j1], pz0 = b3[64+j0], pz1 = b3[64+j1];
#pragma unroll
            for (int i = 0; i < 32; i++) {
                float u = u2[i];
                pw0 += rw0[i]*u; pw1v += rw1[i]*u; pz0 += rz0[i]*u; pz1 += rz1[i]*u;
            }
            float om0 = 2.0f*sigm(pw0), om1 = 2.0f*sigm(pw1v);
            float ze0 = sigm(pz0),      ze1 = sigm(pz1);
            uint2 o;
            o.x = pkh(2.0f*ze0*om0, om0*om0);
            o.y = pkh(2.0f*ze1*om1, om1*om1);
            ABu[pbase + jp*HWn] = o;
        }
    } else {
        for (int j = 0; j < 64; j++) {
            const float* __restrict__ r2 = w3 + (128 + j)*32;
            const float* __restrict__ r3 = w3 + (192 + j)*32;
            float pg = b3[128 + j], pb = b3[192 + j];
#pragma unroll
            for (int i = 0; i < 32; i++) { pg += r2[i]*u2[i]; pb += r3[i]*u2[i]; }
            GB[gbase + j*HWn] = __floats2half2_rn(2.0f * sigm(pg), tanhf(pb));
        }
    }
}

// ---------------- oscillator step: pair-interleaved, 1 px/thread, 8 pairs (16 ch) -------
template <bool LAST>
__global__ void osc_step(const unsigned int* __restrict__ Xin, unsigned int* __restrict__ Xout,
                         unsigned int* __restrict__ V, const unsigned int* __restrict__ F,
                         const uint2* __restrict__ AB,
                         const float* __restrict__ dwk, const float* __restrict__ pwT,
                         float* __restrict__ Xf, float* __restrict__ Vf)
{
    int p = blockIdx.x * blockDim.x + threadIdx.x;
    int pg0 = blockIdx.y << 3;                 // first pair of this group (8 pairs)
    int c0  = pg0 << 1;                        // first channel
    int b  = p >> 14;
    int sp = p & (HWn - 1);
    int y = sp >> 7, x = sp & 127;
    int pbase = b * 32 * HWn + sp;

    // pointwise coupling: acc[k] = sum_c pw[c0+k][c] * x[c], pair loads
    float acc[16];
#pragma unroll
    for (int k = 0; k < 16; k++) acc[k] = 0.f;
#pragma unroll 4
    for (int cp = 0; cp < 32; cp++) {
        float2 xc = uph(Xin[pbase + cp*HWn]);
        const float* __restrict__ w0 = pwT + (2*cp)*64 + c0;
        const float* __restrict__ w1r = w0 + 64;
#pragma unroll
        for (int k = 0; k < 16; k++) acc[k] += w0[k]*xc.x + w1r[k]*xc.y;
    }

    int   yo[3] = { y > 0 ? -Wn : 0, 0, y < Hn-1 ? Wn : 0 };
    float my[3] = { y > 0 ? 1.f : 0.f, 1.f, y < Hn-1 ? 1.f : 0.f };
    float wl = x > 0      ? 1.f : 0.f;
    float wr = x < Wn - 1 ? 1.f : 0.f;

#pragma unroll
    for (int jp = 0; jp < 8; jp++) {
        int cp = pg0 + jp;
        int c  = 2*cp;
        int ub = pbase + cp*HWn;
        float2 tl[3], tc[3], tr[3];
#pragma unroll
        for (int r = 0; r < 3; r++) {
            int rb = ub + yo[r];
            tc[r] = uph(Xin[rb]);
            tl[r] = uph(Xin[rb - 1]);   // masked by wl; off-by-one stays in adjacent ws region
            tr[r] = uph(Xin[rb + 1]);   // masked by wr
        }
        float dws0 = 0.f, dws1 = 0.f;
#pragma unroll
        for (int r = 0; r < 3; r++) {
            float k0 = dwk[c*9 + r*3 + 0] * my[r];
            float k1 = dwk[c*9 + r*3 + 1] * my[r];
            float k2 = dwk[c*9 + r*3 + 2] * my[r];
            float g0 = dwk[(c+1)*9 + r*3 + 0] * my[r];
            float g1 = dwk[(c+1)*9 + r*3 + 1] * my[r];
            float g2 = dwk[(c+1)*9 + r*3 + 2] * my[r];
            dws0 += k0*(wl*tl[r].x) + k1*tc[r].x + k2*(wr*tr[r].x);
            dws1 += g0*(wl*tl[r].y) + g1*tc[r].y + g2*(wr*tr[r].y);
        }
        float xc0 = tc[1].x, xc1 = tc[1].y;
        float2 vv = uph(V[ub]);
        float2 ff = uph(F[ub]);
        uint2 abd = AB[ub];
        float2 ab0 = uph(abd.x);
        float2 ab1 = uph(abd.y);
        float accel0 = ff.x + acc[2*jp]   + dws0 - ab0.x*vv.x - ab0.y*xc0;
        float accel1 = ff.y + acc[2*jp+1] + dws1 - ab1.x*vv.y - ab1.y*xc1;
        float v0 = vv.x + accel0 * DTc;
        float v1 = vv.y + accel1 * DTc;
        float xn0 = xc0 + v0 * DTc;
        float xn1 = xc1 + v1 * DTc;
        if constexpr (!LAST) {
            V[ub]    = pkh(v0, v1);
            Xout[ub] = pkh(xn0, xn1);
        } else {
            int lb = (b*64 + c)*HWn + sp;
            Xf[lb] = xn0;       Xf[lb + HWn] = xn1;
            Vf[lb] = v0;        Vf[lb + HWn] = v1;
        }
    }
}

// ---------------- instance norm stats: one block per channel PAIR ----------------
__global__ void inorm_stats(const unsigned int* __restrict__ Fu, const float* __restrict__ X,
                            float* __restrict__ mu, float* __restrict__ rs)
{
    int bp = blockIdx.x;             // 0..255 : (b*32 + cp)
    int ub = bp * HWn;
    const uint4*  __restrict__ F4 = (const uint4*)(Fu + ub);
    const float4* __restrict__ X0 = (const float4*)(X + 2*(size_t)ub);
    const float4* __restrict__ X1 = X0 + HWn/4;
    float s0 = 0.f, q0 = 0.f, s1 = 0.f, q1 = 0.f;
    for (int i = threadIdx.x; i < HWn/4; i += blockDim.x) {
        uint4 fd = F4[i];
        float4 xa = X0[i], xb = X1[i];
        float2 f0 = uph(fd.x), f1 = uph(fd.y), f2 = uph(fd.z), f3 = uph(fd.w);
        float a0 = f0.x + xa.x, a1 = f1.x + xa.y, a2 = f2.x + xa.z, a3 = f3.x + xa.w;
        float b0 = f0.y + xb.x, b1 = f1.y + xb.y, b2 = f2.y + xb.z, b3 = f3.y + xb.w;
        s0 += (a0 + a1) + (a2 + a3);
        q0 += (a0*a0 + a1*a1) + (a2*a2 + a3*a3);
        s1 += (b0 + b1) + (b2 + b3);
        q1 += (b0*b0 + b1*b1) + (b2*b2 + b3*b3);
    }
#pragma unroll
    for (int o = 32; o > 0; o >>= 1) {
        s0 += __shfl_down(s0, o); q0 += __shfl_down(q0, o);
        s1 += __shfl_down(s1, o); q1 += __shfl_down(q1, o);
    }
    __shared__ float sh[32];
    int w = threadIdx.x >> 6, l = threadIdx.x & 63;
    if (l == 0) { sh[w] = s0; sh[8+w] = q0; sh[16+w] = s1; sh[24+w] = q1; }
    __syncthreads();
    if (threadIdx.x == 0) {
        float S0=0.f, Q0=0.f, S1=0.f, Q1=0.f;
        for (int i = 0; i < 4; i++) { S0+=sh[i]; Q0+=sh[8+i]; S1+=sh[16+i]; Q1+=sh[24+i]; }
        float m0 = S0/(float)HWn, m1 = S1/(float)HWn;
        mu[2*bp]   = m0;  rs[2*bp]   = rsqrtf(Q0/(float)HWn - m0*m0 + EPSc);
        mu[2*bp+1] = m1;  rs[2*bp+1] = rsqrtf(Q1/(float)HWn - m1*m1 + EPSc);
    }
}

// ---------------- instance norm apply + style modulation -> outp (linear fp16) ----------
__global__ void modulate(const unsigned int* __restrict__ Fu, const float* __restrict__ X,
                         const unsigned int* __restrict__ GBu, const float* __restrict__ mu,
                         const float* __restrict__ rs, __half* __restrict__ outp)
{
    int t = blockIdx.x * blockDim.x + threadIdx.x;     // [0, NTOT/8)
    int hw4 = t & 4095;
    int cp  = (t >> 12) & 31;
    int b   = t >> 17;
    int c0 = 2*cp, c1v = c0 + 1;
    int bc0 = b*64 + c0;
    float m0 = mu[bc0], r0 = rs[bc0], m1 = mu[bc0+1], r1 = rs[bc0+1];
    uint4 fd = reinterpret_cast<const uint4*>(Fu)[((b*32 + cp)*HWn >> 2) + hw4];
    int l0 = (bc0*HWn >> 2) + hw4;
    float4 xa = reinterpret_cast<const float4*>(X)[l0];
    float4 xb = reinterpret_cast<const float4*>(X)[l0 + 4096];
    uint4 ga = reinterpret_cast<const uint4*>(GBu)[l0];
    uint4 gb = reinterpret_cast<const uint4*>(GBu)[l0 + 4096];
    float2 f0 = uph(fd.x), f1 = uph(fd.y), f2 = uph(fd.z), f3 = uph(fd.w);
    float2 g0 = uph(ga.x), g1 = uph(ga.y), g2 = uph(ga.z), g3 = uph(ga.w);
    float2 h0 = uph(gb.x), h1 = uph(gb.y), h2 = uph(gb.z), h3 = uph(gb.w);
    // row c0
    float oa0 = g0.x * ((f0.x + xa.x - m0) * r0) + g0.y;
    float oa1 = g1.x * ((f1.x + xa.y - m0) * r0) + g1.y;
    float oa2 = g2.x * ((f2.x + xa.z - m0) * r0) + g2.y;
    float oa3 = g3.x * ((f3.x + xa.w - m0) * r0) + g3.y;
    // row c1
    float ob0 = h0.x * ((f0.y + xb.x - m1) * r1) + h0.y;
    float ob1 = h1.x * ((f1.y + xb.y - m1) * r1) + h1.y;
    float ob2 = h2.x * ((f2.y + xb.z - m1) * r1) + h2.y;
    float ob3 = h3.x * ((f3.y + xb.w - m1) * r1) + h3.y;
    uint2 pa, pb;
    pa.x = pkh(oa0, oa1); pa.y = pkh(oa2, oa3);
    pb.x = pkh(ob0, ob1); pb.y = pkh(ob2, ob3);
    int hw0 = hw4 << 2;
    *reinterpret_cast<uint2*>(outp + (size_t)bc0*HWn + hw0)        = pa;
    *reinterpret_cast<uint2*>(outp + (size_t)(bc0+1)*HWn + hw0)    = pb;
    (void)c1v;
}

// ---------------- refine: LDS weights + packed fp16 hfma2 phases 2/3 (unchanged) --------
__global__ __launch_bounds__(512)
void refine(const __half* __restrict__ outp,
            const float* __restrict__ rdwk, const float* __restrict__ rdwb,
            const float* __restrict__ pw1T, const float* __restrict__ pb1,
            const float* __restrict__ pw2T, const float* __restrict__ pb2,
            const float* __restrict__ ls, float* __restrict__ out)
{
    __shared__ __half rv_s[64][128];
    __shared__ __half act_s[64][128];
    __shared__ __half w1s[64][64];
    __shared__ __half w2s[64][64];
    __shared__ float  dwks[576];
    __shared__ __half2 pb1h[32], pb2h[32];
    __shared__ float  rdwbs[64], lss[64];
    int t = threadIdx.x;
    for (int i = t; i < 4096; i += 512) {
        w1s[i>>6][i&63] = __float2half(pw1T[i]);
        w2s[i>>6][i&63] = __float2half(pw2T[i]);
    }
    for (int i = t; i < 576; i += 512) dwks[i] = rdwk[i];
    if (t < 64) { rdwbs[t]=rdwb[t]; lss[t]=ls[t]; }
    if (t < 32) {
        pb1h[t] = __floats2half2_rn(pb1[2*t], pb1[2*t+1]);
        pb2h[t] = __floats2half2_rn(pb2[2*t], pb2[2*t+1]);
    }

    int l = t & 127;
    int w = t >> 7;
    int c0 = w << 4;
    int p = blockIdx.x * 128 + l;
    int b  = p >> 14;
    int sp = p & (HWn - 1);
    int y = sp >> 7, x = sp & 127;
    int base = b * Cn * HWn + sp;

    int   yo[3] = { y > 0 ? -Wn : 0, 0, y < Hn-1 ? Wn : 0 };
    int   xo[3] = { x > 0 ? -1  : 0, 0, x < Wn-1 ? 1  : 0 };
    float myv[3] = { y > 0 ? 1.f : 0.f, 1.f, y < Hn-1 ? 1.f : 0.f };
    float mxv[3] = { x > 0 ? 1.f : 0.f, 1.f, x < Wn-1 ? 1.f : 0.f };
    float mm[9]; int oo[9];
#pragma unroll
    for (int dy = 0; dy < 3; dy++)
#pragma unroll
        for (int dx = 0; dx < 3; dx++) { mm[dy*3+dx] = myv[dy]*mxv[dx]; oo[dy*3+dx] = yo[dy]+xo[dx]; }
    __syncthreads();

#pragma unroll
    for (int cc = 0; cc < 16; cc++) {
        int c = c0 + cc;
        int cb = base + c*HWn;
        float rv = rdwbs[c];
#pragma unroll
        for (int tt = 0; tt < 9; tt++)
            rv += (dwks[c*9 + tt] * mm[tt]) * __half2float(outp[cb + oo[tt]]);
        rv_s[c][l] = __float2half(rv);
    }
    __syncthreads();

    __half2 acc2[8];
#pragma unroll
    for (int q = 0; q < 8; q++) acc2[q] = pb1h[(c0 >> 1) + q];
#pragma unroll 4
    for (int c = 0; c < 64; c++) {
        __half2 rvh = __half2half2(rv_s[c][l]);
        const __half2* wrow = (const __half2*)&w1s[c][c0];
#pragma unroll
        for (int q = 0; q < 8; q++) acc2[q] = __hfma2(wrow[q], rvh, acc2[q]);
    }
#pragma unroll
    for (int q = 0; q < 8; q++) {
        float2 a = __half22float2(acc2[q]);
        float a0 = a.x > 0.f ? a.x : 0.2f*a.x;
        float a1 = a.y > 0.f ? a.y : 0.2f*a.y;
        act_s[c0 + 2*q][l]     = __float2half(a0);
        act_s[c0 + 2*q + 1][l] = __float2half(a1);
    }
    __syncthreads();

#pragma unroll
    for (int q = 0; q < 8; q++) acc2[q] = pb2h[(c0 >> 1) + q];
#pragma unroll 4
    for (int j = 0; j < 64; j++) {
        __half2 ah = __half2half2(act_s[j][l]);
        const __half2* wrow = (const __half2*)&w2s[j][c0];
#pragma unroll
        for (int q = 0; q < 8; q++) acc2[q] = __hfma2(wrow[q], ah, acc2[q]);
    }
#pragma unroll
    for (int q = 0; q < 8; q++) {
        float2 r = __half22float2(acc2[q]);
        int ca = c0 + 2*q, cb2 = c0 + 2*q + 1;
        int ba = base + ca*HWn, bb = base + cb2*HWn;
        out[ba] = __half2float(outp[ba]) + lss[ca] * r.x;
        out[bb] = __half2float(outp[bb]) + lss[cb2] * r.y;
    }
}

extern "C" void kernel_launch(void* const* d_in, const int* in_sizes, int n_in,
                              void* d_out, int out_size, void* d_ws, size_t ws_size,
                              hipStream_t stream)
{
    (void)in_sizes; (void)n_in; (void)out_size; (void)ws_size;
    const float* force   = (const float*)d_in[0];
    const float* style   = (const float*)d_in[1];
    const float* illum   = (const float*)d_in[2];
    const float* h_w1    = (const float*)d_in[3];
    const float* h_b1    = (const float*)d_in[4];
    const float* h_w2    = (const float*)d_in[5];
    const float* h_b2    = (const float*)d_in[6];
    const float* h_w3    = (const float*)d_in[7];
    const float* h_b3    = (const float*)d_in[8];
    const float* dw_k    = (const float*)d_in[9];
    const float* pw_w    = (const float*)d_in[10];
    const float* r_dw_k  = (const float*)d_in[11];
    const float* r_dw_b  = (const float*)d_in[12];
    const float* r_pw1_w = (const float*)d_in[13];
    const float* r_pw1_b = (const float*)d_in[14];
    const float* r_pw2_w = (const float*)d_in[15];
    const float* r_pw2_b = (const float*)d_in[16];
    const float* lscale  = (const float*)d_in[17];

    float* out  = (float*)d_out;              // holds GB (half2) until refine overwrites
    float* Xf32 = out + (size_t)NTOT;         // final x fp32
    float* Vf32 = out + 2*(size_t)NTOT;       // final v fp32
    unsigned int* GBu = (unsigned int*)out;

    char* w = (char*)d_ws;
    uint2*        ABu = (uint2*)w;        w += (size_t)NTOT*4;   // pair layout, 33.5 MB
    unsigned int* Fu  = (unsigned int*)w; w += (size_t)NTOT*2;
    unsigned int* XAu = (unsigned int*)w; w += (size_t)NTOT*2;
    unsigned int* XBu = (unsigned int*)w; w += (size_t)NTOT*2;
    unsigned int* Vu  = (unsigned int*)w; w += (size_t)NTOT*2;
    float* w1T  = (float*)w;
    float* c1   = w1T + 2048;
    float* pwT  = c1 + 32;
    float* pw1T = pwT + 4096;
    float* pw2T = pw1T + 4096;
    float* mu   = pw2T + 4096;
    float* rs   = mu + 512;
    __half* outp = (__half*)ABu;              // AB dead after last osc step

    fuseF0<<<NTOT/2048, 256, 0, stream>>>((const float4*)force, (const float4*)illum,
                                          Fu, XAu, Vu);
    prep<<<1, 256, 0, stream>>>(style, h_w1, h_b1, pw_w, r_pw1_w, r_pw2_w,
                                w1T, c1, pwT, pw1T, pw2T);
    hyper2<<<dim3(NPIX/256, 2), 256, 0, stream>>>(Fu, w1T, c1, h_w2, h_b2, h_w3, h_b3,
                                                  ABu, (__half2*)GBu);
    for (int s = 1; s <= 8; s++) {
        const unsigned int* xin = (s & 1) ? XAu : XBu;
        unsigned int*      xout = (s & 1) ? XBu : XAu;
        osc_step<false><<<dim3(NPIX/256, 4), 256, 0, stream>>>(xin, xout, Vu, Fu, ABu,
                                                               dw_k, pwT, nullptr, nullptr);
    }
    // step 9 (odd): reads XAu, writes fp32 x,v directly to d_out (linear)
    osc_step<true><<<dim3(NPIX/256, 4), 256, 0, stream>>>(XAu, XBu, Vu, Fu, ABu,
                                                          dw_k, pwT, Xf32, Vf32);
    inorm_stats<<<Bn*32, 256, 0, stream>>>(Fu, Xf32, mu, rs);
    modulate<<<NTOT/2048, 256, 0, stream>>>(Fu, Xf32, GBu, mu, rs, outp);
    refine<<<NPIX/128, 512, 0, stream>>>(outp, r_dw_k, r_dw_b, pw1T, r_pw1_b,
                                         pw2T, r_pw2_b, lscale, out);
}